// Round 9
// baseline (255.361 us; speedup 1.0000x reference)
//
#include <hip/hip_runtime.h>
#include <hip/hip_bf16.h>
#include <hip/hip_fp16.h>

typedef _Float16 f16;
typedef _Float16 f16x4 __attribute__((ext_vector_type(4)));
typedef _Float16 f16x8 __attribute__((ext_vector_type(8)));
typedef float f32x4 __attribute__((ext_vector_type(4)));

#define MFMA16(a, b, c) __builtin_amdgcn_mfma_f32_16x16x32_f16(a, b, c, 0, 0, 0)

__device__ __forceinline__ float fexp2(float x) {
#if __has_builtin(__builtin_amdgcn_exp2f)
    return __builtin_amdgcn_exp2f(x);
#else
    return exp2f(x);
#endif
}

// ---------------- prep: f32 -> f16 convert ----------------
__global__ void k_convert_x(const float* __restrict__ in, f16* __restrict__ out, int n4) {
    int i = blockIdx.x * blockDim.x + threadIdx.x;
    if (i >= n4) return;
    float4 v = ((const float4*)in)[i];
    f16x4 o = {(f16)v.x, (f16)v.y, (f16)v.z, (f16)v.w};
    ((f16x4*)out)[i] = o;
}

// ---------------- prep: transpose f32[K][N] -> f16[N][K] ----------------
__global__ __launch_bounds__(256) void k_transpose(const float* __restrict__ in,
                                                   f16* __restrict__ out, int K, int N) {
    __shared__ f16 tile[64][72];
    int n0 = blockIdx.x * 64, k0 = blockIdx.y * 64;
    int t = threadIdx.x;
    int r = t >> 2, cb = (t & 3) * 16;
    const float* src = in + (size_t)(k0 + r) * N + n0 + cb;
#pragma unroll
    for (int j = 0; j < 4; ++j) {
        float4 v = ((const float4*)src)[j];
        tile[r][cb + 4 * j + 0] = (f16)v.x;
        tile[r][cb + 4 * j + 1] = (f16)v.y;
        tile[r][cb + 4 * j + 2] = (f16)v.z;
        tile[r][cb + 4 * j + 3] = (f16)v.w;
    }
    __syncthreads();
    int nl = t >> 2, kb = (t & 3) * 16;
    f16* dst = out + (size_t)(n0 + nl) * K + k0 + kb;
#pragma unroll
    for (int j = 0; j < 2; ++j) {
        f16x8 o;
#pragma unroll
        for (int e = 0; e < 8; ++e) o[e] = tile[kb + 8 * j + e][nl];
        *(f16x8*)(dst + 8 * j) = o;
    }
}

// ---------------- shared GEMM core (round-6 proven): manual staging, stride-40 LDS ----------------
__device__ __forceinline__ void gemm_core(const f16* __restrict__ A, const f16* __restrict__ Bt,
                                          int m0, int n0, int t, int lane, int wr, int wc,
                                          f16* As, f16* Bs, f32x4 acc[4][4]) {
    for (int kt = 0; kt < 24; ++kt) {
#pragma unroll
        for (int i = 0; i < 2; ++i) {
            int c = t + i * 256;
            int row = c >> 2, cb = (c & 3) * 8;
            f16x8 va = *(const f16x8*)(A + (size_t)(m0 + row) * 768 + kt * 32 + cb);
            f16x8 vb = *(const f16x8*)(Bt + (size_t)(n0 + row) * 768 + kt * 32 + cb);
            *(f16x8*)(As + row * 40 + cb) = va;
            *(f16x8*)(Bs + row * 40 + cb) = vb;
        }
        __syncthreads();
        f16x8 a[4], b[4];
#pragma unroll
        for (int i = 0; i < 4; ++i)
            a[i] = *(const f16x8*)(As + (wr * 64 + i * 16 + (lane & 15)) * 40 + (lane >> 4) * 8);
#pragma unroll
        for (int j = 0; j < 4; ++j)
            b[j] = *(const f16x8*)(Bs + (wc * 64 + j * 16 + (lane & 15)) * 40 + (lane >> 4) * 8);
#pragma unroll
        for (int i = 0; i < 4; ++i)
#pragma unroll
            for (int j = 0; j < 4; ++j) acc[i][j] = MFMA16(a[i], b[j], acc[i][j]);
        __syncthreads();
    }
}

// ---------------- QKV GEMM -> Qh (row layout), Kf/Vf (MFMA-fragment-linear layouts) ----------------
// Kf: (bh, kt, f=s*2+half, lane=hi*16+lo, e) = K[token=kt*64+s*16+lo][d=half*32+hi*8+e]
// Vf: (bh, kt, f=jd*2+half, lane=hi*16+lo, e) = V[token=kt*64+half*32+hi*8+e][d=jd*16+lo]
__global__ __launch_bounds__(256) void k_qkv_gemm(const f16* __restrict__ A, const f16* __restrict__ Bt,
                                                  const float* __restrict__ bias,
                                                  f16* __restrict__ Qh, f16* __restrict__ Kf,
                                                  f16* __restrict__ Vf) {
    __shared__ f16 As[128 * 40];
    __shared__ f16 Bs[128 * 40];
    int m0 = blockIdx.x * 128, n0 = blockIdx.y * 128;
    int t = threadIdx.x, lane = t & 63, w = t >> 6;
    int wr = w >> 1, wc = w & 1;
    f32x4 zero = {0.f, 0.f, 0.f, 0.f};
    f32x4 acc[4][4];
#pragma unroll
    for (int i = 0; i < 4; ++i)
#pragma unroll
        for (int j = 0; j < 4; ++j) acc[i][j] = zero;

    gemm_core(A, Bt, m0, n0, t, lane, wr, wc, As, Bs, acc);

    // Q prescale folds softmax scale AND log2(e): 0.125 * log2(e)
    const float QSCALE = 0.18033688011112042f;
#pragma unroll
    for (int j = 0; j < 4; ++j) {
        int n = n0 + wc * 64 + j * 16 + (lane & 15);
        int which = n / 768;
        int rem = n - which * 768;
        int h = rem >> 6, d = rem & 63;
        float bv = bias[n];
#pragma unroll
        for (int i = 0; i < 4; ++i) {
            int m = m0 + wr * 64 + i * 16 + ((lane >> 4) << 2);
            int bb = m >> 11, tt = m & 2047;
            int bh = bb * 12 + h;
            if (which == 2) {
                int kt = tt >> 6;
                int half = (tt & 63) >> 5, hi = (tt & 31) >> 3, e0 = tt & 7;
                int jd = d >> 4, lo = d & 15;
                size_t addr = (((size_t)bh * 32 + kt) * 8 + jd * 2 + half) * 512 +
                              (size_t)(hi * 16 + lo) * 8 + e0;
                f16x4 pk;
#pragma unroll
                for (int r = 0; r < 4; ++r) pk[r] = (f16)(acc[i][j][r] + bv);
                *(f16x4*)(Vf + addr) = pk;
            } else if (which == 0) {
#pragma unroll
                for (int r = 0; r < 4; ++r)
                    Qh[((size_t)bh * 2048 + tt + r) * 64 + d] = (f16)((acc[i][j][r] + bv) * QSCALE);
            } else {
                int half = d >> 5, hi = (d & 31) >> 3, e = d & 7;
#pragma unroll
                for (int r = 0; r < 4; ++r) {
                    int tr = tt + r;
                    int kt = tr >> 6, row = tr & 63;
                    int s = row >> 4, lo = row & 15;
                    size_t addr = (((size_t)bh * 32 + kt) * 8 + s * 2 + half) * 512 +
                                  (size_t)(hi * 16 + lo) * 8 + e;
                    Kf[addr] = (f16)(acc[i][j][r] + bv);
                }
            }
        }
    }
}

// ---------------- O GEMM: A = (valp0 + valp1) f32 partials -> f16, B = wo_t ----------------
__global__ __launch_bounds__(256) void k_o_gemm(const float* __restrict__ P0, const float* __restrict__ P1,
                                                const f16* __restrict__ Bt,
                                                const float* __restrict__ bias,
                                                float* __restrict__ out) {
    __shared__ f16 As[128 * 40];
    __shared__ f16 Bs[128 * 40];
    int m0 = blockIdx.x * 128, n0 = blockIdx.y * 128;
    int t = threadIdx.x, lane = t & 63, w = t >> 6;
    int wr = w >> 1, wc = w & 1;
    f32x4 zero = {0.f, 0.f, 0.f, 0.f};
    f32x4 acc[4][4];
#pragma unroll
    for (int i = 0; i < 4; ++i)
#pragma unroll
        for (int j = 0; j < 4; ++j) acc[i][j] = zero;

    for (int kt = 0; kt < 24; ++kt) {
#pragma unroll
        for (int i = 0; i < 2; ++i) {
            int c = t + i * 256;
            int row = c >> 2, cb = (c & 3) * 8;
            const float* a0 = P0 + (size_t)(m0 + row) * 768 + kt * 32 + cb;
            const float* a1 = P1 + (size_t)(m0 + row) * 768 + kt * 32 + cb;
            f32x4 u0 = *(const f32x4*)a0 + *(const f32x4*)a1;
            f32x4 u1 = *(const f32x4*)(a0 + 4) + *(const f32x4*)(a1 + 4);
            f16x8 av = {(f16)u0[0], (f16)u0[1], (f16)u0[2], (f16)u0[3],
                        (f16)u1[0], (f16)u1[1], (f16)u1[2], (f16)u1[3]};
            *(f16x8*)(As + row * 40 + cb) = av;
            f16x8 vb = *(const f16x8*)(Bt + (size_t)(n0 + row) * 768 + kt * 32 + cb);
            *(f16x8*)(Bs + row * 40 + cb) = vb;
        }
        __syncthreads();
        f16x8 a[4], b[4];
#pragma unroll
        for (int i = 0; i < 4; ++i)
            a[i] = *(const f16x8*)(As + (wr * 64 + i * 16 + (lane & 15)) * 40 + (lane >> 4) * 8);
#pragma unroll
        for (int j = 0; j < 4; ++j)
            b[j] = *(const f16x8*)(Bs + (wc * 64 + j * 16 + (lane & 15)) * 40 + (lane >> 4) * 8);
#pragma unroll
        for (int i = 0; i < 4; ++i)
#pragma unroll
            for (int j = 0; j < 4; ++j) acc[i][j] = MFMA16(a[i], b[j], acc[i][j]);
        __syncthreads();
    }

#pragma unroll
    for (int j = 0; j < 4; ++j) {
        int n = n0 + wc * 64 + j * 16 + (lane & 15);
        float bv = bias[n];
#pragma unroll
        for (int i = 0; i < 4; ++i) {
            int m = m0 + wr * 64 + i * 16 + ((lane >> 4) << 2);
#pragma unroll
            for (int r = 0; r < 4; ++r) out[(size_t)(m + r) * 768 + n] = acc[i][j][r] + bv;
        }
    }
}

// ---------------- lsum: split-k partial row-sums of exp2(S'), XCD-swizzled ----------------
// grid 3072 1D (= 8 XCD x 384; 384 = 3 heads x 128). Each XCD owns 3 heads -> K L2-resident.
__global__ __launch_bounds__(256) void k_lsum(const f16* __restrict__ Qh, const f16* __restrict__ Kf,
                                              float* __restrict__ lpart) {
    int orig = blockIdx.x;
    int swz = (orig & 7) * 384 + (orig >> 3);
    int bh = swz >> 7, rem = swz & 127, qt = rem >> 2, kc = rem & 3;
    int q0 = qt * 64;
    int t = threadIdx.x, lane = t & 63, w = t >> 6;
    const f16* qbase = Qh + ((size_t)bh * 2048 + q0 + w * 16) * 64;
    const f16* kfb = Kf + (size_t)bh * 32 * 4096 + (size_t)lane * 8;

    f16x8 aq[2];
#pragma unroll
    for (int f = 0; f < 2; ++f)
        aq[f] = *(const f16x8*)(qbase + (size_t)(lane & 15) * 64 + f * 32 + (lane >> 4) * 8);
    f32x4 zero = {0.f, 0.f, 0.f, 0.f};

    auto LOADK = [&](f16x8* dst, int kt) {
        const f16* kp = kfb + (size_t)kt * 4096;
#pragma unroll
        for (int f = 0; f < 8; ++f) dst[f] = *(const f16x8*)(kp + f * 512);
    };
    auto QKT = [&](const f16x8* kf, f32x4* s4) {
#pragma unroll
        for (int s = 0; s < 4; ++s) {
            s4[s] = MFMA16(aq[0], kf[2 * s], zero);
            s4[s] = MFMA16(aq[1], kf[2 * s + 1], s4[s]);
        }
    };

    f16x8 ka[8], kb2[8];
    float lsum[4] = {0.f, 0.f, 0.f, 0.f};
    int base = kc * 8;
    LOADK(ka, base);
    for (int i = 0; i < 8; i += 2) {
        f32x4 s4[4];
        LOADK(kb2, base + i + 1);
        QKT(ka, s4);
#pragma unroll
        for (int s = 0; s < 4; ++s)
#pragma unroll
            for (int r = 0; r < 4; ++r) lsum[r] += fexp2(s4[s][r]);
        LOADK(ka, base + ((i + 2) & 7));
        QKT(kb2, s4);
#pragma unroll
        for (int s = 0; s < 4; ++s)
#pragma unroll
            for (int r = 0; r < 4; ++r) lsum[r] += fexp2(s4[s][r]);
    }
#pragma unroll
    for (int r = 0; r < 4; ++r) {
#pragma unroll
        for (int off = 1; off < 16; off <<= 1) lsum[r] += __shfl_xor(lsum[r], off, 64);
    }
    int qrow = q0 + w * 16 + (lane >> 4) * 4;
    float* lp = lpart + (size_t)kc * 49152 + (size_t)bh * 2048;
#pragma unroll
    for (int r = 0; r < 4; ++r)
        if ((lane & 15) == r) lp[qrow + r] = lsum[r];
}

// ---------------- attention pass 2: k-split x2, 32-wide subtiles, 16+ waves/CU ----------------
// grid 1536 (8 XCD x 192 = 3 heads x 64; 64 = 32 qt x 2 kc2). Each block: 64 q-rows x
// 1024 keys (half the range) in 32 subtiles of 32 keys. PV partials -> valp[kc2] (f32);
// k_o_gemm sums them. VGPR budget ~100 -> launch_bounds(256,4) for 16 waves/CU.
__global__ __launch_bounds__(256, 4) void k_attn(const f16* __restrict__ Qh, const f16* __restrict__ Kf,
                                                 const f16* __restrict__ Vf,
                                                 const float* __restrict__ lpart,
                                                 float* __restrict__ attn, float* __restrict__ valp) {
    __shared__ __align__(16) float Ps32_all[4][16 * 36];
    int orig = blockIdx.x;
    int swz = (orig & 7) * 192 + (orig >> 3);   // bijective: 1536 = 8*192
    int bh = swz >> 6, rem = swz & 63, qt = rem >> 1, kc2 = rem & 1;
    int q0 = qt * 64;
    int t = threadIdx.x, lane = t & 63, w = t >> 6;

    const f16* qbase = Qh + ((size_t)bh * 2048 + q0 + w * 16) * 64;
    const f16* kfb = Kf + (size_t)bh * 32 * 4096 + (size_t)lane * 8;
    const f16* vfb = Vf + (size_t)bh * 32 * 4096 + (size_t)lane * 8;

    f16x8 aq[2];
#pragma unroll
    for (int f = 0; f < 2; ++f)
        aq[f] = *(const f16x8*)(qbase + (size_t)(lane & 15) * 64 + f * 32 + (lane >> 4) * 8);
    f32x4 zero = {0.f, 0.f, 0.f, 0.f};

    // linv from split-k partials
    int qrow = q0 + w * 16 + (lane >> 4) * 4;
    float linv[4];
#pragma unroll
    for (int r = 0; r < 4; ++r) {
        float s = 0.f;
#pragma unroll
        for (int kc = 0; kc < 4; ++kc)
            s += lpart[(size_t)kc * 49152 + (size_t)bh * 2048 + qrow + r];
        linv[r] = 1.0f / s;
    }

    // ks = 32-key subtile index (global key offset = ks*32)
    auto LOADK32 = [&](f16x8* dst, int ks) {
        const f16* p = kfb + (size_t)ks * 2048;
#pragma unroll
        for (int f = 0; f < 4; ++f) dst[f] = *(const f16x8*)(p + f * 512);
    };
    auto LOADV32 = [&](f16x8* dst, int ks) {
        const f16* p = vfb + (size_t)(ks >> 1) * 4096 + (size_t)(ks & 1) * 512;
#pragma unroll
        for (int jd = 0; jd < 4; ++jd) dst[jd] = *(const f16x8*)(p + jd * 1024);
    };

    f32x4 accv[4];
#pragma unroll
    for (int j = 0; j < 4; ++j) accv[j] = zero;
    float* Ps = Ps32_all[w];   // wave-private 16 x 36 f32
    float* attn_base = attn + ((size_t)bh * 2048 + q0 + w * 16) * 2048;
    f16x8 ka[4], kb2[4], vbuf[4];
    int base = kc2 * 32;

    auto step2 = [&](f16x8* curK, f16x8* nxtK, int ks) {
        // 1) loads first: this subtile's V, next subtile's K
        LOADV32(vbuf, ks);
        LOADK32(nxtK, base + (((ks + 1) - base) & 31));
        // 2) QK^T (16q x 32k): 4 MFMA
        f32x4 s4[2];
        s4[0] = MFMA16(aq[0], curK[0], zero);
        s4[0] = MFMA16(aq[1], curK[1], s4[0]);
        s4[1] = MFMA16(aq[0], curK[2], zero);
        s4[1] = MFMA16(aq[1], curK[3], s4[1]);
        // 3) softmax -> wave-private f32 LDS tile [16q][32k], stride 36
#pragma unroll
        for (int sp = 0; sp < 2; ++sp) {
#pragma unroll
            for (int r = 0; r < 4; ++r) {
                float p = fexp2(s4[sp][r]) * linv[r];
                Ps[((lane >> 4) * 4 + r) * 36 + sp * 16 + (lane & 15)] = p;
            }
        }
        // 4) PV A-fragment from tile: lane reads P[q=lane&15][k=(lane>>4)*8..+7]
        f16x8 pa;
        {
            const float* pr = Ps + (lane & 15) * 36 + (lane >> 4) * 8;
            f32x4 lo = *(const f32x4*)(pr);
            f32x4 hi = *(const f32x4*)(pr + 4);
            f16x8 pf = {(f16)lo[0], (f16)lo[1], (f16)lo[2], (f16)lo[3],
                        (f16)hi[0], (f16)hi[1], (f16)hi[2], (f16)hi[3]};
            pa = pf;
        }
        // 5) coalesced attention stores: 2x dwordx4 (128B row-runs)
        float* ab = attn_base + ks * 32;
#pragma unroll
        for (int i = 0; i < 2; ++i) {
            int row = i * 8 + (lane >> 3);
            int col = (lane & 7) * 4;
            f32x4 v = *(const f32x4*)(Ps + row * 36 + col);
            *(f32x4*)(ab + (size_t)row * 2048 + col) = v;
        }
        // 6) PV MFMA: 4 (stores are newer than vbuf -> never block its wait)
#pragma unroll
        for (int jd = 0; jd < 4; ++jd) accv[jd] = MFMA16(pa, vbuf[jd], accv[jd]);
    };

    LOADK32(ka, base);
    for (int i = 0; i < 32; i += 2) {
        step2(ka, kb2, base + i);
        step2(kb2, ka, base + i + 1);
    }

    // epilogue: PV partials (f32) -> valp[kc2]
    int b = bh / 12, h = bh - b * 12;
    float* vp = valp + (size_t)kc2 * 3145728;
#pragma unroll
    for (int j = 0; j < 4; ++j) {
#pragma unroll
        for (int r = 0; r < 4; ++r) {
            int rowg = b * 2048 + q0 + w * 16 + (lane >> 4) * 4 + r;
            int col = h * 64 + j * 16 + (lane & 15);
            vp[(size_t)rowg * 768 + col] = accv[j][r];
        }
    }
}

extern "C" void kernel_launch(void* const* d_in, const int* in_sizes, int n_in,
                              void* d_out, int out_size, void* d_ws, size_t ws_size,
                              hipStream_t stream) {
    const float* x = (const float*)d_in[0];
    const float* wqkv = (const float*)d_in[1];
    const float* bqkv = (const float*)d_in[2];
    const float* wo = (const float*)d_in[3];
    const float* bo = (const float*)d_in[4];

    float* out_o = (float*)d_out;                          // [2,2048,768] fp32
    float* out_attn = out_o + (size_t)2 * 2048 * 768;      // [2,12,2048,2048] fp32

    f16* ws = (f16*)d_ws;
    f16* xh = ws;                       // 3,145,728 f16
    f16* wqkv_t = xh + 3145728;         // 1,769,472  [2304][768]
    f16* wo_t = wqkv_t + 1769472;       // 589,824    [768][768]
    f16* Qh = wo_t + 589824;            // [bh][t][64], pre-scaled
    f16* Kf = Qh + 3145728;             // fragment-linear K
    f16* Vf = Kf + 3145728;             // fragment-linear V
    float* lpart = (float*)(Vf + 3145728);    // [4][24*2048] f32 split-k lsum partials
    float* valp = lpart + 196608;             // [2][4096][768] f32 PV partials

    k_convert_x<<<3072, 256, 0, stream>>>(x, xh, 786432);
    k_transpose<<<dim3(36, 12), 256, 0, stream>>>(wqkv, wqkv_t, 768, 2304);
    k_transpose<<<dim3(12, 12), 256, 0, stream>>>(wo, wo_t, 768, 768);
    k_qkv_gemm<<<dim3(32, 18), 256, 0, stream>>>(xh, wqkv_t, bqkv, Qh, Kf, Vf);
    k_lsum<<<3072, 256, 0, stream>>>(Qh, Kf, lpart);
    k_attn<<<1536, 256, 0, stream>>>(Qh, Kf, Vf, lpart, out_attn, valp);
    k_o_gemm<<<dim3(32, 6), 256, 0, stream>>>(valp, valp + 3145728, wo_t, bo, out_o);
}

// Round 10
// 227.388 us; speedup vs baseline: 1.1230x; 1.1230x over previous
//
#include <hip/hip_runtime.h>
#include <hip/hip_bf16.h>
#include <hip/hip_fp16.h>

typedef _Float16 f16;
typedef _Float16 f16x4 __attribute__((ext_vector_type(4)));
typedef _Float16 f16x8 __attribute__((ext_vector_type(8)));
typedef float f32x4 __attribute__((ext_vector_type(4)));

#define MFMA16(a, b, c) __builtin_amdgcn_mfma_f32_16x16x32_f16(a, b, c, 0, 0, 0)

__device__ __forceinline__ float fexp2(float x) {
#if __has_builtin(__builtin_amdgcn_exp2f)
    return __builtin_amdgcn_exp2f(x);
#else
    return exp2f(x);
#endif
}

// ---------------- prep: f32 -> f16 convert ----------------
__global__ void k_convert_x(const float* __restrict__ in, f16* __restrict__ out, int n4) {
    int i = blockIdx.x * blockDim.x + threadIdx.x;
    if (i >= n4) return;
    float4 v = ((const float4*)in)[i];
    f16x4 o = {(f16)v.x, (f16)v.y, (f16)v.z, (f16)v.w};
    ((f16x4*)out)[i] = o;
}

// ---------------- prep: transpose f32[K][N] -> f16[N][K] ----------------
__global__ __launch_bounds__(256) void k_transpose(const float* __restrict__ in,
                                                   f16* __restrict__ out, int K, int N) {
    __shared__ f16 tile[64][72];
    int n0 = blockIdx.x * 64, k0 = blockIdx.y * 64;
    int t = threadIdx.x;
    int r = t >> 2, cb = (t & 3) * 16;
    const float* src = in + (size_t)(k0 + r) * N + n0 + cb;
#pragma unroll
    for (int j = 0; j < 4; ++j) {
        float4 v = ((const float4*)src)[j];
        tile[r][cb + 4 * j + 0] = (f16)v.x;
        tile[r][cb + 4 * j + 1] = (f16)v.y;
        tile[r][cb + 4 * j + 2] = (f16)v.z;
        tile[r][cb + 4 * j + 3] = (f16)v.w;
    }
    __syncthreads();
    int nl = t >> 2, kb = (t & 3) * 16;
    f16* dst = out + (size_t)(n0 + nl) * K + k0 + kb;
#pragma unroll
    for (int j = 0; j < 2; ++j) {
        f16x8 o;
#pragma unroll
        for (int e = 0; e < 8; ++e) o[e] = tile[kb + 8 * j + e][nl];
        *(f16x8*)(dst + 8 * j) = o;
    }
}

// ---------------- shared GEMM core (round-6 proven): manual staging, stride-40 LDS ----------------
__device__ __forceinline__ void gemm_core(const f16* __restrict__ A, const f16* __restrict__ Bt,
                                          int m0, int n0, int t, int lane, int wr, int wc,
                                          f16* As, f16* Bs, f32x4 acc[4][4]) {
    for (int kt = 0; kt < 24; ++kt) {
#pragma unroll
        for (int i = 0; i < 2; ++i) {
            int c = t + i * 256;
            int row = c >> 2, cb = (c & 3) * 8;
            f16x8 va = *(const f16x8*)(A + (size_t)(m0 + row) * 768 + kt * 32 + cb);
            f16x8 vb = *(const f16x8*)(Bt + (size_t)(n0 + row) * 768 + kt * 32 + cb);
            *(f16x8*)(As + row * 40 + cb) = va;
            *(f16x8*)(Bs + row * 40 + cb) = vb;
        }
        __syncthreads();
        f16x8 a[4], b[4];
#pragma unroll
        for (int i = 0; i < 4; ++i)
            a[i] = *(const f16x8*)(As + (wr * 64 + i * 16 + (lane & 15)) * 40 + (lane >> 4) * 8);
#pragma unroll
        for (int j = 0; j < 4; ++j)
            b[j] = *(const f16x8*)(Bs + (wc * 64 + j * 16 + (lane & 15)) * 40 + (lane >> 4) * 8);
#pragma unroll
        for (int i = 0; i < 4; ++i)
#pragma unroll
            for (int j = 0; j < 4; ++j) acc[i][j] = MFMA16(a[i], b[j], acc[i][j]);
        __syncthreads();
    }
}

// ---------------- QKV GEMM -> Qh (row layout), Kf/Vf (MFMA-fragment-linear layouts) ----------------
// Kf: (bh, kt, f=s*2+half, lane=hi*16+lo, e) = K[token=kt*64+s*16+lo][d=half*32+hi*8+e]
// Vf: (bh, kt, f=jd*2+half, lane=hi*16+lo, e) = V[token=kt*64+half*32+hi*8+e][d=jd*16+lo]
__global__ __launch_bounds__(256) void k_qkv_gemm(const f16* __restrict__ A, const f16* __restrict__ Bt,
                                                  const float* __restrict__ bias,
                                                  f16* __restrict__ Qh, f16* __restrict__ Kf,
                                                  f16* __restrict__ Vf) {
    __shared__ f16 As[128 * 40];
    __shared__ f16 Bs[128 * 40];
    int m0 = blockIdx.x * 128, n0 = blockIdx.y * 128;
    int t = threadIdx.x, lane = t & 63, w = t >> 6;
    int wr = w >> 1, wc = w & 1;
    f32x4 zero = {0.f, 0.f, 0.f, 0.f};
    f32x4 acc[4][4];
#pragma unroll
    for (int i = 0; i < 4; ++i)
#pragma unroll
        for (int j = 0; j < 4; ++j) acc[i][j] = zero;

    gemm_core(A, Bt, m0, n0, t, lane, wr, wc, As, Bs, acc);

    // Q prescale folds softmax scale AND log2(e): 0.125 * log2(e)
    const float QSCALE = 0.18033688011112042f;
#pragma unroll
    for (int j = 0; j < 4; ++j) {
        int n = n0 + wc * 64 + j * 16 + (lane & 15);
        int which = n / 768;
        int rem = n - which * 768;
        int h = rem >> 6, d = rem & 63;
        float bv = bias[n];
#pragma unroll
        for (int i = 0; i < 4; ++i) {
            int m = m0 + wr * 64 + i * 16 + ((lane >> 4) << 2);
            int bb = m >> 11, tt = m & 2047;
            int bh = bb * 12 + h;
            if (which == 2) {
                int kt = tt >> 6;
                int half = (tt & 63) >> 5, hi = (tt & 31) >> 3, e0 = tt & 7;
                int jd = d >> 4, lo = d & 15;
                size_t addr = (((size_t)bh * 32 + kt) * 8 + jd * 2 + half) * 512 +
                              (size_t)(hi * 16 + lo) * 8 + e0;
                f16x4 pk;
#pragma unroll
                for (int r = 0; r < 4; ++r) pk[r] = (f16)(acc[i][j][r] + bv);
                *(f16x4*)(Vf + addr) = pk;
            } else if (which == 0) {
#pragma unroll
                for (int r = 0; r < 4; ++r)
                    Qh[((size_t)bh * 2048 + tt + r) * 64 + d] = (f16)((acc[i][j][r] + bv) * QSCALE);
            } else {
                int half = d >> 5, hi = (d & 31) >> 3, e = d & 7;
#pragma unroll
                for (int r = 0; r < 4; ++r) {
                    int tr = tt + r;
                    int kt = tr >> 6, row = tr & 63;
                    int s = row >> 4, lo = row & 15;
                    size_t addr = (((size_t)bh * 32 + kt) * 8 + s * 2 + half) * 512 +
                                  (size_t)(hi * 16 + lo) * 8 + e;
                    Kf[addr] = (f16)(acc[i][j][r] + bv);
                }
            }
        }
    }
}

// ---------------- O GEMM: valh[4096][768] f16 x wo_t[768][768]^T + bias -> out fp32 ----------------
__global__ __launch_bounds__(256) void k_o_gemm(const f16* __restrict__ A, const f16* __restrict__ Bt,
                                                const float* __restrict__ bias,
                                                float* __restrict__ out) {
    __shared__ f16 As[128 * 40];
    __shared__ f16 Bs[128 * 40];
    int m0 = blockIdx.x * 128, n0 = blockIdx.y * 128;
    int t = threadIdx.x, lane = t & 63, w = t >> 6;
    int wr = w >> 1, wc = w & 1;
    f32x4 zero = {0.f, 0.f, 0.f, 0.f};
    f32x4 acc[4][4];
#pragma unroll
    for (int i = 0; i < 4; ++i)
#pragma unroll
        for (int j = 0; j < 4; ++j) acc[i][j] = zero;

    gemm_core(A, Bt, m0, n0, t, lane, wr, wc, As, Bs, acc);

#pragma unroll
    for (int j = 0; j < 4; ++j) {
        int n = n0 + wc * 64 + j * 16 + (lane & 15);
        float bv = bias[n];
#pragma unroll
        for (int i = 0; i < 4; ++i) {
            int m = m0 + wr * 64 + i * 16 + ((lane >> 4) << 2);
#pragma unroll
            for (int r = 0; r < 4; ++r) out[(size_t)(m + r) * 768 + n] = acc[i][j][r] + bv;
        }
    }
}

// ---------------- lsum: split-k partial row-sums of exp2(S'), XCD-swizzled ----------------
// grid 3072 1D (= 8 XCD x 384; 384 = 3 heads x 128). Each XCD owns 3 heads -> K L2-resident.
__global__ __launch_bounds__(256) void k_lsum(const f16* __restrict__ Qh, const f16* __restrict__ Kf,
                                              float* __restrict__ lpart) {
    int orig = blockIdx.x;
    int swz = (orig & 7) * 384 + (orig >> 3);
    int bh = swz >> 7, rem = swz & 127, qt = rem >> 2, kc = rem & 3;
    int q0 = qt * 64;
    int t = threadIdx.x, lane = t & 63, w = t >> 6;
    const f16* qbase = Qh + ((size_t)bh * 2048 + q0 + w * 16) * 64;
    const f16* kfb = Kf + (size_t)bh * 32 * 4096 + (size_t)lane * 8;

    f16x8 aq[2];
#pragma unroll
    for (int f = 0; f < 2; ++f)
        aq[f] = *(const f16x8*)(qbase + (size_t)(lane & 15) * 64 + f * 32 + (lane >> 4) * 8);
    f32x4 zero = {0.f, 0.f, 0.f, 0.f};

    auto LOADK = [&](f16x8* dst, int kt) {
        const f16* kp = kfb + (size_t)kt * 4096;
#pragma unroll
        for (int f = 0; f < 8; ++f) dst[f] = *(const f16x8*)(kp + f * 512);
    };
    auto QKT = [&](const f16x8* kf, f32x4* s4) {
#pragma unroll
        for (int s = 0; s < 4; ++s) {
            s4[s] = MFMA16(aq[0], kf[2 * s], zero);
            s4[s] = MFMA16(aq[1], kf[2 * s + 1], s4[s]);
        }
    };

    f16x8 ka[8], kb2[8];
    float lsum[4] = {0.f, 0.f, 0.f, 0.f};
    int base = kc * 8;
    LOADK(ka, base);
    for (int i = 0; i < 8; i += 2) {
        f32x4 s4[4];
        LOADK(kb2, base + i + 1);
        QKT(ka, s4);
#pragma unroll
        for (int s = 0; s < 4; ++s)
#pragma unroll
            for (int r = 0; r < 4; ++r) lsum[r] += fexp2(s4[s][r]);
        LOADK(ka, base + ((i + 2) & 7));
        QKT(kb2, s4);
#pragma unroll
        for (int s = 0; s < 4; ++s)
#pragma unroll
            for (int r = 0; r < 4; ++r) lsum[r] += fexp2(s4[s][r]);
    }
#pragma unroll
    for (int r = 0; r < 4; ++r) {
#pragma unroll
        for (int off = 1; off < 16; off <<= 1) lsum[r] += __shfl_xor(lsum[r], off, 64);
    }
    int qrow = q0 + w * 16 + (lane >> 4) * 4;
    float* lp = lpart + (size_t)kc * 49152 + (size_t)bh * 2048;
#pragma unroll
    for (int r = 0; r < 4; ++r)
        if ((lane & 15) == r) lp[qrow + r] = lsum[r];
}

// ---------------- attention pass 2 (single pass, round-8 proven): stream P + PV ----------------
__global__ __launch_bounds__(256, 3) void k_attn(const f16* __restrict__ Qh, const f16* __restrict__ Kf,
                                                 const f16* __restrict__ Vf,
                                                 const float* __restrict__ lpart,
                                                 float* __restrict__ attn, f16* __restrict__ valh) {
    __shared__ __align__(16) float Ps32_all[4][16 * 68];
    int orig = blockIdx.x;
    int swz = (orig & 7) * 96 + (orig >> 3);   // 768 blocks, 8 XCDs, bijective
    int bh = swz >> 5, qt = swz & 31;
    int q0 = qt * 64;
    int t = threadIdx.x, lane = t & 63, w = t >> 6;

    const f16* qbase = Qh + ((size_t)bh * 2048 + q0 + w * 16) * 64;
    const f16* kfb = Kf + (size_t)bh * 32 * 4096 + (size_t)lane * 8;
    const f16* vfb = Vf + (size_t)bh * 32 * 4096 + (size_t)lane * 8;

    f16x8 aq[2];
#pragma unroll
    for (int f = 0; f < 2; ++f)
        aq[f] = *(const f16x8*)(qbase + (size_t)(lane & 15) * 64 + f * 32 + (lane >> 4) * 8);
    f32x4 zero = {0.f, 0.f, 0.f, 0.f};

    // linv from split-k partials
    int qrow = q0 + w * 16 + (lane >> 4) * 4;
    float linv[4];
#pragma unroll
    for (int r = 0; r < 4; ++r) {
        float s = 0.f;
#pragma unroll
        for (int kc = 0; kc < 4; ++kc)
            s += lpart[(size_t)kc * 49152 + (size_t)bh * 2048 + qrow + r];
        linv[r] = 1.0f / s;
    }

    auto LOADK = [&](f16x8* dst, int kt) {
        const f16* kp = kfb + (size_t)kt * 4096;
#pragma unroll
        for (int f = 0; f < 8; ++f) dst[f] = *(const f16x8*)(kp + f * 512);
    };
    auto QKT = [&](const f16x8* kf, f32x4* s4) {
#pragma unroll
        for (int s = 0; s < 4; ++s) {
            s4[s] = MFMA16(aq[0], kf[2 * s], zero);
            s4[s] = MFMA16(aq[1], kf[2 * s + 1], s4[s]);
        }
    };

    f32x4 accv[4];
#pragma unroll
    for (int j = 0; j < 4; ++j) accv[j] = zero;
    float* Ps = Ps32_all[w];   // wave-private 16 x 68 f32
    float* attn_base = attn + ((size_t)bh * 2048 + q0 + w * 16) * 2048;
    f16x8 ka[8], kb2[8], vbuf[8];

    auto step2 = [&](f16x8* curK, f16x8* nxtK, int kt) {
        // 1) loads first (V oldest, then next K) so load-waits never retire stores
        {
            const f16* vp = vfb + (size_t)kt * 4096;
#pragma unroll
            for (int f = 0; f < 8; ++f) vbuf[f] = *(const f16x8*)(vp + f * 512);
        }
        LOADK(nxtK, (kt + 1) & 31);
        // 2) QK^T
        f32x4 s4[4];
        QKT(curK, s4);
        // 3) softmax -> wave-private f32 LDS tile [q][k], stride 68
#pragma unroll
        for (int s = 0; s < 4; ++s) {
#pragma unroll
            for (int r = 0; r < 4; ++r) {
                float p = fexp2(s4[s][r]) * linv[r];
                Ps[((lane >> 4) * 4 + r) * 68 + s * 16 + (lane & 15)] = p;
            }
        }
        // 4) PV A-fragment (f16) from the tile
        f16x8 pa[2];
#pragma unroll
        for (int half = 0; half < 2; ++half) {
            const float* pr = Ps + (lane & 15) * 68 + half * 32 + (lane >> 4) * 8;
            f32x4 lo = *(const f32x4*)(pr);
            f32x4 hi = *(const f32x4*)(pr + 4);
            f16x8 pf = {(f16)lo[0], (f16)lo[1], (f16)lo[2], (f16)lo[3],
                        (f16)hi[0], (f16)hi[1], (f16)hi[2], (f16)hi[3]};
            pa[half] = pf;
        }
        // 5) coalesced attention stores: 4x dwordx4 (256B runs per 16-lane group)
        float* ab = attn_base + kt * 64;
#pragma unroll
        for (int i = 0; i < 4; ++i) {
            int row = i * 4 + (lane >> 4);
            int col = (lane & 15) * 4;
            f32x4 v = *(const f32x4*)(Ps + row * 68 + col);
            *(f32x4*)(ab + (size_t)row * 2048 + col) = v;
        }
        // 6) PV MFMA
#pragma unroll
        for (int jd = 0; jd < 4; ++jd) {
            accv[jd] = MFMA16(pa[0], vbuf[2 * jd], accv[jd]);
            accv[jd] = MFMA16(pa[1], vbuf[2 * jd + 1], accv[jd]);
        }
    };

    LOADK(ka, 0);
    for (int kt = 0; kt < 32; kt += 2) {
        step2(ka, kb2, kt);
        step2(kb2, ka, kt + 1);
    }

    // epilogue: values -> valh [b*2048+t][h*64+d] f16
    int b = bh / 12, h = bh - b * 12;
#pragma unroll
    for (int j = 0; j < 4; ++j) {
#pragma unroll
        for (int r = 0; r < 4; ++r) {
            int rowg = b * 2048 + q0 + w * 16 + (lane >> 4) * 4 + r;
            int col = h * 64 + j * 16 + (lane & 15);
            valh[(size_t)rowg * 768 + col] = (f16)accv[j][r];
        }
    }
}

extern "C" void kernel_launch(void* const* d_in, const int* in_sizes, int n_in,
                              void* d_out, int out_size, void* d_ws, size_t ws_size,
                              hipStream_t stream) {
    const float* x = (const float*)d_in[0];
    const float* wqkv = (const float*)d_in[1];
    const float* bqkv = (const float*)d_in[2];
    const float* wo = (const float*)d_in[3];
    const float* bo = (const float*)d_in[4];

    float* out_o = (float*)d_out;                          // [2,2048,768] fp32
    float* out_attn = out_o + (size_t)2 * 2048 * 768;      // [2,12,2048,2048] fp32

    f16* ws = (f16*)d_ws;
    f16* xh = ws;                       // 3,145,728 f16
    f16* wqkv_t = xh + 3145728;         // 1,769,472  [2304][768]
    f16* wo_t = wqkv_t + 1769472;       // 589,824    [768][768]
    f16* Qh = wo_t + 589824;            // [bh][t][64], pre-scaled
    f16* Kf = Qh + 3145728;             // fragment-linear K
    f16* Vf = Kf + 3145728;             // fragment-linear V
    f16* valh = Vf + 3145728;           // [4096][768]
    float* lpart = (float*)(valh + 3145728);  // [4][24*2048] f32 split-k lsum partials

    k_convert_x<<<3072, 256, 0, stream>>>(x, xh, 786432);
    k_transpose<<<dim3(36, 12), 256, 0, stream>>>(wqkv, wqkv_t, 768, 2304);
    k_transpose<<<dim3(12, 12), 256, 0, stream>>>(wo, wo_t, 768, 768);
    k_qkv_gemm<<<dim3(32, 18), 256, 0, stream>>>(xh, wqkv_t, bqkv, Qh, Kf, Vf);
    k_lsum<<<3072, 256, 0, stream>>>(Qh, Kf, lpart);
    k_attn<<<768, 256, 0, stream>>>(Qh, Kf, Vf, lpart, out_attn, valh);
    k_o_gemm<<<dim3(32, 6), 256, 0, stream>>>(valh, wo_t, bo, out_o);
}

// Round 11
// 203.202 us; speedup vs baseline: 1.2567x; 1.1190x over previous
//
#include <hip/hip_runtime.h>
#include <hip/hip_bf16.h>
#include <hip/hip_fp16.h>

typedef _Float16 f16;
typedef _Float16 f16x4 __attribute__((ext_vector_type(4)));
typedef _Float16 f16x8 __attribute__((ext_vector_type(8)));
typedef float f32x4 __attribute__((ext_vector_type(4)));

#define MFMA16(a, b, c) __builtin_amdgcn_mfma_f32_16x16x32_f16(a, b, c, 0, 0, 0)

__device__ __forceinline__ float fexp2(float x) {
#if __has_builtin(__builtin_amdgcn_exp2f)
    return __builtin_amdgcn_exp2f(x);
#else
    return exp2f(x);
#endif
}

typedef __attribute__((address_space(1))) const void gconst_t;
typedef __attribute__((address_space(3))) void lds_t;
__device__ __forceinline__ void gload16(const f16* g, f16* l) {
    __builtin_amdgcn_global_load_lds((gconst_t*)g, (lds_t*)l, 16, 0, 0);
}

// ---------------- prep: f32 -> f16 convert ----------------
__global__ void k_convert_x(const float* __restrict__ in, f16* __restrict__ out, int n4) {
    int i = blockIdx.x * blockDim.x + threadIdx.x;
    if (i >= n4) return;
    float4 v = ((const float4*)in)[i];
    f16x4 o = {(f16)v.x, (f16)v.y, (f16)v.z, (f16)v.w};
    ((f16x4*)out)[i] = o;
}

// ---------------- prep: transpose f32[K][N] -> f16[N][K] ----------------
__global__ __launch_bounds__(256) void k_transpose(const float* __restrict__ in,
                                                   f16* __restrict__ out, int K, int N) {
    __shared__ f16 tile[64][72];
    int n0 = blockIdx.x * 64, k0 = blockIdx.y * 64;
    int t = threadIdx.x;
    int r = t >> 2, cb = (t & 3) * 16;
    const float* src = in + (size_t)(k0 + r) * N + n0 + cb;
#pragma unroll
    for (int j = 0; j < 4; ++j) {
        float4 v = ((const float4*)src)[j];
        tile[r][cb + 4 * j + 0] = (f16)v.x;
        tile[r][cb + 4 * j + 1] = (f16)v.y;
        tile[r][cb + 4 * j + 2] = (f16)v.z;
        tile[r][cb + 4 * j + 3] = (f16)v.w;
    }
    __syncthreads();
    int nl = t >> 2, kb = (t & 3) * 16;
    f16* dst = out + (size_t)(n0 + nl) * K + k0 + kb;
#pragma unroll
    for (int j = 0; j < 2; ++j) {
        f16x8 o;
#pragma unroll
        for (int e = 0; e < 8; ++e) o[e] = tile[kb + 8 * j + e][nl];
        *(f16x8*)(dst + 8 * j) = o;
    }
}

// ---------------- shared GEMM core (R8): global_load_lds + XOR-swizzled LDS ----------------
__device__ __forceinline__ void gemm_core(const f16* __restrict__ A, const f16* __restrict__ Bt,
                                          int m0, int n0, int lane, int w, int wr, int wc,
                                          f16* As, f16* Bs, f32x4 acc[4][4]) {
    int prow = lane >> 2, pc = lane & 3;
    int lrow = prow ^ ((prow >> 2) & 1);
    int lcol = (pc ^ (lrow & 3)) * 8;
    int rsw = (lane & 7) << 3;
    for (int kt = 0; kt < 24; ++kt) {
        const f16* ab = A + (size_t)(m0 + w * 32 + lrow) * 768 + kt * 32 + lcol;
        const f16* bb = Bt + (size_t)(n0 + w * 32 + lrow) * 768 + kt * 32 + lcol;
        gload16(ab, As + (w * 32) * 32);
        gload16(ab + (size_t)16 * 768, As + (w * 32 + 16) * 32);
        gload16(bb, Bs + (w * 32) * 32);
        gload16(bb + (size_t)16 * 768, Bs + (w * 32 + 16) * 32);
        __syncthreads();
        f16x8 a[4], b[4];
#pragma unroll
        for (int i = 0; i < 4; ++i) {
            int idx = (wr * 64 + i * 16 + (lane & 15)) * 32 + (lane >> 4) * 8;
            a[i] = *(const f16x8*)(As + (idx ^ rsw));
        }
#pragma unroll
        for (int j = 0; j < 4; ++j) {
            int idx = (wc * 64 + j * 16 + (lane & 15)) * 32 + (lane >> 4) * 8;
            b[j] = *(const f16x8*)(Bs + (idx ^ rsw));
        }
#pragma unroll
        for (int i = 0; i < 4; ++i)
#pragma unroll
            for (int j = 0; j < 4; ++j) acc[i][j] = MFMA16(a[i], b[j], acc[i][j]);
        __syncthreads();
    }
}

// ---------------- QKV GEMM -> Qh (row layout), Kf/Vf (fragment-linear) ----------------
__global__ __launch_bounds__(256) void k_qkv_gemm(const f16* __restrict__ A, const f16* __restrict__ Bt,
                                                  const float* __restrict__ bias,
                                                  f16* __restrict__ Qh, f16* __restrict__ Kf,
                                                  f16* __restrict__ Vf) {
    __shared__ __align__(16) f16 As[128 * 32];
    __shared__ __align__(16) f16 Bs[128 * 32];
    int m0 = blockIdx.x * 128, n0 = blockIdx.y * 128;
    int t = threadIdx.x, lane = t & 63, w = t >> 6;
    int wr = w >> 1, wc = w & 1;
    f32x4 zero = {0.f, 0.f, 0.f, 0.f};
    f32x4 acc[4][4];
#pragma unroll
    for (int i = 0; i < 4; ++i)
#pragma unroll
        for (int j = 0; j < 4; ++j) acc[i][j] = zero;

    gemm_core(A, Bt, m0, n0, lane, w, wr, wc, As, Bs, acc);

    const float QSCALE = 0.18033688011112042f;  // 0.125 * log2(e)
#pragma unroll
    for (int j = 0; j < 4; ++j) {
        int n = n0 + wc * 64 + j * 16 + (lane & 15);
        int which = n / 768;
        int rem = n - which * 768;
        int h = rem >> 6, d = rem & 63;
        float bv = bias[n];
#pragma unroll
        for (int i = 0; i < 4; ++i) {
            int m = m0 + wr * 64 + i * 16 + ((lane >> 4) << 2);
            int bb = m >> 11, tt = m & 2047;
            int bh = bb * 12 + h;
            if (which == 2) {
                int kt = tt >> 6;
                int half = (tt & 63) >> 5, hi = (tt & 31) >> 3, e0 = tt & 7;
                int jd = d >> 4, lo = d & 15;
                size_t addr = (((size_t)bh * 32 + kt) * 8 + jd * 2 + half) * 512 +
                              (size_t)(hi * 16 + lo) * 8 + e0;
                f16x4 pk;
#pragma unroll
                for (int r = 0; r < 4; ++r) pk[r] = (f16)(acc[i][j][r] + bv);
                *(f16x4*)(Vf + addr) = pk;
            } else if (which == 0) {
#pragma unroll
                for (int r = 0; r < 4; ++r)
                    Qh[((size_t)bh * 2048 + tt + r) * 64 + d] = (f16)((acc[i][j][r] + bv) * QSCALE);
            } else {
                int half = d >> 5, hi = (d & 31) >> 3, e = d & 7;
#pragma unroll
                for (int r = 0; r < 4; ++r) {
                    int tr = tt + r;
                    int kt = tr >> 6, row = tr & 63;
                    int s = row >> 4, lo = row & 15;
                    size_t addr = (((size_t)bh * 32 + kt) * 8 + s * 2 + half) * 512 +
                                  (size_t)(hi * 16 + lo) * 8 + e;
                    Kf[addr] = (f16)(acc[i][j][r] + bv);
                }
            }
        }
    }
}

// ---------------- O GEMM ----------------
__global__ __launch_bounds__(256) void k_o_gemm(const f16* __restrict__ A, const f16* __restrict__ Bt,
                                                const float* __restrict__ bias,
                                                float* __restrict__ out) {
    __shared__ __align__(16) f16 As[128 * 32];
    __shared__ __align__(16) f16 Bs[128 * 32];
    int m0 = blockIdx.x * 128, n0 = blockIdx.y * 128;
    int t = threadIdx.x, lane = t & 63, w = t >> 6;
    int wr = w >> 1, wc = w & 1;
    f32x4 zero = {0.f, 0.f, 0.f, 0.f};
    f32x4 acc[4][4];
#pragma unroll
    for (int i = 0; i < 4; ++i)
#pragma unroll
        for (int j = 0; j < 4; ++j) acc[i][j] = zero;

    gemm_core(A, Bt, m0, n0, lane, w, wr, wc, As, Bs, acc);

#pragma unroll
    for (int j = 0; j < 4; ++j) {
        int n = n0 + wc * 64 + j * 16 + (lane & 15);
        float bv = bias[n];
#pragma unroll
        for (int i = 0; i < 4; ++i) {
            int m = m0 + wr * 64 + i * 16 + ((lane >> 4) << 2);
#pragma unroll
            for (int r = 0; r < 4; ++r) out[(size_t)(m + r) * 768 + n] = acc[i][j][r] + bv;
        }
    }
}

// ---------------- lsum: split-k partial row-sums, SWAPPED QK^T (S^T layout) ----------------
// grid (32 qt, 24 bh, 4 kc) as in R8. mfma(K,Q): lane holds S[k=s*16+(lane>>4)*4+r][q=lane&15]
// -> lane-local partial sum + 2 shuffles (xor 16, 32); coalesced 64B result write.
__global__ __launch_bounds__(256) void k_lsum(const f16* __restrict__ Qh, const f16* __restrict__ Kf,
                                              float* __restrict__ lpart) {
    int qt = blockIdx.x, bh = blockIdx.y, kc = blockIdx.z;
    int q0 = qt * 64;
    int t = threadIdx.x, lane = t & 63, w = t >> 6;
    const f16* qbase = Qh + ((size_t)bh * 2048 + q0 + w * 16) * 64;
    const f16* kfb = Kf + (size_t)bh * 32 * 4096 + (size_t)lane * 8;

    f16x8 aq[2];
#pragma unroll
    for (int f = 0; f < 2; ++f)
        aq[f] = *(const f16x8*)(qbase + (size_t)(lane & 15) * 64 + f * 32 + (lane >> 4) * 8);
    f32x4 zero = {0.f, 0.f, 0.f, 0.f};

    auto LOADK = [&](f16x8* dst, int kt) {
        const f16* kp = kfb + (size_t)kt * 4096;
#pragma unroll
        for (int f = 0; f < 8; ++f) dst[f] = *(const f16x8*)(kp + f * 512);
    };
    auto QKTS = [&](const f16x8* kf, f32x4* s4) {   // swapped: A=K, B=Q
#pragma unroll
        for (int s = 0; s < 4; ++s) {
            s4[s] = MFMA16(kf[2 * s], aq[0], zero);
            s4[s] = MFMA16(kf[2 * s + 1], aq[1], s4[s]);
        }
    };

    f16x8 ka[8], kb2[8];
    float lsum = 0.f;
    int base = kc * 8;
    LOADK(ka, base);
    for (int i = 0; i < 8; i += 2) {
        f32x4 s4[4];
        LOADK(kb2, base + i + 1);
        QKTS(ka, s4);
#pragma unroll
        for (int s = 0; s < 4; ++s)
#pragma unroll
            for (int r = 0; r < 4; ++r) lsum += fexp2(s4[s][r]);
        LOADK(ka, base + ((i + 2) & 7));
        QKTS(kb2, s4);
#pragma unroll
        for (int s = 0; s < 4; ++s)
#pragma unroll
            for (int r = 0; r < 4; ++r) lsum += fexp2(s4[s][r]);
    }
    lsum += __shfl_xor(lsum, 16, 64);
    lsum += __shfl_xor(lsum, 32, 64);
    float* lp = lpart + (size_t)kc * 49152 + (size_t)bh * 2048 + q0 + w * 16;
    if (lane < 16) lp[lane] = lsum;
}

// ---------------- attention pass 2: swapped QK^T; b128 LDS writes; scalar linv ----------------
__global__ __launch_bounds__(256, 3) void k_attn(const f16* __restrict__ Qh, const f16* __restrict__ Kf,
                                                 const f16* __restrict__ Vf,
                                                 const float* __restrict__ lpart,
                                                 float* __restrict__ attn, f16* __restrict__ valh) {
    __shared__ __align__(16) float Ps32_all[4][16 * 68];
    int orig = blockIdx.x;
    int swz = (orig & 7) * 96 + (orig >> 3);   // 768 blocks, 8 XCDs, bijective
    int bh = swz >> 5, qt = swz & 31;
    int q0 = qt * 64;
    int t = threadIdx.x, lane = t & 63, w = t >> 6;

    const f16* qbase = Qh + ((size_t)bh * 2048 + q0 + w * 16) * 64;
    const f16* kfb = Kf + (size_t)bh * 32 * 4096 + (size_t)lane * 8;
    const f16* vfb = Vf + (size_t)bh * 32 * 4096 + (size_t)lane * 8;

    f16x8 aq[2];
#pragma unroll
    for (int f = 0; f < 2; ++f)
        aq[f] = *(const f16x8*)(qbase + (size_t)(lane & 15) * 64 + f * 32 + (lane >> 4) * 8);
    f32x4 zero = {0.f, 0.f, 0.f, 0.f};

    // scalar linv: this lane's q-row = q0 + w*16 + (lane&15)
    float linv;
    {
        size_t qoff = (size_t)bh * 2048 + q0 + w * 16 + (lane & 15);
        float s = 0.f;
#pragma unroll
        for (int kc = 0; kc < 4; ++kc) s += lpart[(size_t)kc * 49152 + qoff];
        linv = 1.0f / s;
    }

    auto LOADK = [&](f16x8* dst, int kt) {
        const f16* kp = kfb + (size_t)kt * 4096;
#pragma unroll
        for (int f = 0; f < 8; ++f) dst[f] = *(const f16x8*)(kp + f * 512);
    };
    auto QKTS = [&](const f16x8* kf, f32x4* s4) {   // swapped: A=K, B=Q
#pragma unroll
        for (int s = 0; s < 4; ++s) {
            s4[s] = MFMA16(kf[2 * s], aq[0], zero);
            s4[s] = MFMA16(kf[2 * s + 1], aq[1], s4[s]);
        }
    };

    f32x4 accv[4];
#pragma unroll
    for (int j = 0; j < 4; ++j) accv[j] = zero;
    float* Ps = Ps32_all[w];   // wave-private 16 x 68 f32, [q][k]
    float* attn_base = attn + ((size_t)bh * 2048 + q0 + w * 16) * 2048;
    f16x8 ka[8], kb2[8], vbuf[8];

    auto step2 = [&](f16x8* curK, f16x8* nxtK, int kt) {
        // 1) loads first (V oldest, then next K) so load-waits never retire stores
        {
            const f16* vp = vfb + (size_t)kt * 4096;
#pragma unroll
            for (int f = 0; f < 8; ++f) vbuf[f] = *(const f16x8*)(vp + f * 512);
        }
        LOADK(nxtK, (kt + 1) & 31);
        // 2) swapped QK^T: lane holds S[k = s*16+(lane>>4)*4+r][q = lane&15]
        f32x4 s4[4];
        QKTS(curK, s4);
        // 3) softmax -> Ps[q][k]: one f32x4 (4 consecutive k) per s -> 4x ds_write_b128
#pragma unroll
        for (int s = 0; s < 4; ++s) {
            f32x4 pv;
#pragma unroll
            for (int r = 0; r < 4; ++r) pv[r] = fexp2(s4[s][r]) * linv;
            *(f32x4*)(Ps + (lane & 15) * 68 + s * 16 + (lane >> 4) * 4) = pv;
        }
        // 4) PV A-fragment (f16) from the tile (layout unchanged)
        f16x8 pa[2];
#pragma unroll
        for (int half = 0; half < 2; ++half) {
            const float* pr = Ps + (lane & 15) * 68 + half * 32 + (lane >> 4) * 8;
            f32x4 lo = *(const f32x4*)(pr);
            f32x4 hi = *(const f32x4*)(pr + 4);
            f16x8 pf = {(f16)lo[0], (f16)lo[1], (f16)lo[2], (f16)lo[3],
                        (f16)hi[0], (f16)hi[1], (f16)hi[2], (f16)hi[3]};
            pa[half] = pf;
        }
        // 5) coalesced attention stores: 4x dwordx4 (256B runs per 16-lane group)
        float* ab = attn_base + kt * 64;
#pragma unroll
        for (int i = 0; i < 4; ++i) {
            int row = i * 4 + (lane >> 4);
            int col = (lane & 15) * 4;
            f32x4 v = *(const f32x4*)(Ps + row * 68 + col);
            *(f32x4*)(ab + (size_t)row * 2048 + col) = v;
        }
        // 6) PV MFMA
#pragma unroll
        for (int jd = 0; jd < 4; ++jd) {
            accv[jd] = MFMA16(pa[0], vbuf[2 * jd], accv[jd]);
            accv[jd] = MFMA16(pa[1], vbuf[2 * jd + 1], accv[jd]);
        }
    };

    LOADK(ka, 0);
    for (int kt = 0; kt < 32; kt += 2) {
        step2(ka, kb2, kt);
        step2(kb2, ka, kt + 1);
    }

    // epilogue: values -> valh [b*2048+t][h*64+d] f16
    int b = bh / 12, h = bh - b * 12;
#pragma unroll
    for (int j = 0; j < 4; ++j) {
#pragma unroll
        for (int r = 0; r < 4; ++r) {
            int rowg = b * 2048 + q0 + w * 16 + (lane >> 4) * 4 + r;
            int col = h * 64 + j * 16 + (lane & 15);
            valh[(size_t)rowg * 768 + col] = (f16)accv[j][r];
        }
    }
}

extern "C" void kernel_launch(void* const* d_in, const int* in_sizes, int n_in,
                              void* d_out, int out_size, void* d_ws, size_t ws_size,
                              hipStream_t stream) {
    const float* x = (const float*)d_in[0];
    const float* wqkv = (const float*)d_in[1];
    const float* bqkv = (const float*)d_in[2];
    const float* wo = (const float*)d_in[3];
    const float* bo = (const float*)d_in[4];

    float* out_o = (float*)d_out;                          // [2,2048,768] fp32
    float* out_attn = out_o + (size_t)2 * 2048 * 768;      // [2,12,2048,2048] fp32

    f16* ws = (f16*)d_ws;
    f16* xh = ws;                       // 3,145,728 f16
    f16* wqkv_t = xh + 3145728;         // [2304][768]
    f16* wo_t = wqkv_t + 1769472;       // [768][768]
    f16* Qh = wo_t + 589824;            // [bh][t][64], pre-scaled
    f16* Kf = Qh + 3145728;             // fragment-linear K
    f16* Vf = Kf + 3145728;             // fragment-linear V
    f16* valh = Vf + 3145728;           // [4096][768]
    float* lpart = (float*)(valh + 3145728);  // [4][24*2048] f32 split-k partials

    k_convert_x<<<3072, 256, 0, stream>>>(x, xh, 786432);
    k_transpose<<<dim3(36, 12), 256, 0, stream>>>(wqkv, wqkv_t, 768, 2304);
    k_transpose<<<dim3(12, 12), 256, 0, stream>>>(wo, wo_t, 768, 768);
    k_qkv_gemm<<<dim3(32, 18), 256, 0, stream>>>(xh, wqkv_t, bqkv, Qh, Kf, Vf);
    k_lsum<<<dim3(32, 24, 4), 256, 0, stream>>>(Qh, Kf, lpart);
    k_attn<<<768, 256, 0, stream>>>(Qh, Kf, Vf, lpart, out_attn, valh);
    k_o_gemm<<<dim3(32, 6), 256, 0, stream>>>(valh, wo_t, bo, out_o);
}

// Round 12
// 199.992 us; speedup vs baseline: 1.2769x; 1.0160x over previous
//
#include <hip/hip_runtime.h>
#include <hip/hip_bf16.h>
#include <hip/hip_fp16.h>

typedef _Float16 f16;
typedef _Float16 f16x4 __attribute__((ext_vector_type(4)));
typedef _Float16 f16x8 __attribute__((ext_vector_type(8)));
typedef float f32x4 __attribute__((ext_vector_type(4)));

#define MFMA16(a, b, c) __builtin_amdgcn_mfma_f32_16x16x32_f16(a, b, c, 0, 0, 0)

__device__ __forceinline__ float fexp2(float x) {
#if __has_builtin(__builtin_amdgcn_exp2f)
    return __builtin_amdgcn_exp2f(x);
#else
    return exp2f(x);
#endif
}

typedef __attribute__((address_space(1))) const void gconst_t;
typedef __attribute__((address_space(3))) void lds_t;
__device__ __forceinline__ void gload16(const f16* g, f16* l) {
    __builtin_amdgcn_global_load_lds((gconst_t*)g, (lds_t*)l, 16, 0, 0);
}

// ---------------- prep: f32 -> f16 convert ----------------
__global__ void k_convert_x(const float* __restrict__ in, f16* __restrict__ out, int n4) {
    int i = blockIdx.x * blockDim.x + threadIdx.x;
    if (i >= n4) return;
    float4 v = ((const float4*)in)[i];
    f16x4 o = {(f16)v.x, (f16)v.y, (f16)v.z, (f16)v.w};
    ((f16x4*)out)[i] = o;
}

// ---------------- prep: transpose f32[K][N] -> f16[N][K] ----------------
__global__ __launch_bounds__(256) void k_transpose(const float* __restrict__ in,
                                                   f16* __restrict__ out, int K, int N) {
    __shared__ f16 tile[64][72];
    int n0 = blockIdx.x * 64, k0 = blockIdx.y * 64;
    int t = threadIdx.x;
    int r = t >> 2, cb = (t & 3) * 16;
    const float* src = in + (size_t)(k0 + r) * N + n0 + cb;
#pragma unroll
    for (int j = 0; j < 4; ++j) {
        float4 v = ((const float4*)src)[j];
        tile[r][cb + 4 * j + 0] = (f16)v.x;
        tile[r][cb + 4 * j + 1] = (f16)v.y;
        tile[r][cb + 4 * j + 2] = (f16)v.z;
        tile[r][cb + 4 * j + 3] = (f16)v.w;
    }
    __syncthreads();
    int nl = t >> 2, kb = (t & 3) * 16;
    f16* dst = out + (size_t)(n0 + nl) * K + k0 + kb;
#pragma unroll
    for (int j = 0; j < 2; ++j) {
        f16x8 o;
#pragma unroll
        for (int e = 0; e < 8; ++e) o[e] = tile[kb + 8 * j + e][nl];
        *(f16x8*)(dst + 8 * j) = o;
    }
}

// ---------------- shared GEMM core (R8): global_load_lds + XOR-swizzled LDS ----------------
__device__ __forceinline__ void gemm_core(const f16* __restrict__ A, const f16* __restrict__ Bt,
                                          int m0, int n0, int lane, int w, int wr, int wc,
                                          f16* As, f16* Bs, f32x4 acc[4][4]) {
    int prow = lane >> 2, pc = lane & 3;
    int lrow = prow ^ ((prow >> 2) & 1);
    int lcol = (pc ^ (lrow & 3)) * 8;
    int rsw = (lane & 7) << 3;
    for (int kt = 0; kt < 24; ++kt) {
        const f16* ab = A + (size_t)(m0 + w * 32 + lrow) * 768 + kt * 32 + lcol;
        const f16* bb = Bt + (size_t)(n0 + w * 32 + lrow) * 768 + kt * 32 + lcol;
        gload16(ab, As + (w * 32) * 32);
        gload16(ab + (size_t)16 * 768, As + (w * 32 + 16) * 32);
        gload16(bb, Bs + (w * 32) * 32);
        gload16(bb + (size_t)16 * 768, Bs + (w * 32 + 16) * 32);
        __syncthreads();
        f16x8 a[4], b[4];
#pragma unroll
        for (int i = 0; i < 4; ++i) {
            int idx = (wr * 64 + i * 16 + (lane & 15)) * 32 + (lane >> 4) * 8;
            a[i] = *(const f16x8*)(As + (idx ^ rsw));
        }
#pragma unroll
        for (int j = 0; j < 4; ++j) {
            int idx = (wc * 64 + j * 16 + (lane & 15)) * 32 + (lane >> 4) * 8;
            b[j] = *(const f16x8*)(Bs + (idx ^ rsw));
        }
#pragma unroll
        for (int i = 0; i < 4; ++i)
#pragma unroll
            for (int j = 0; j < 4; ++j) acc[i][j] = MFMA16(a[i], b[j], acc[i][j]);
        __syncthreads();
    }
}

// ---------------- QKV GEMM -> Qh (row layout), Kf/Vf (fragment-linear) ----------------
__global__ __launch_bounds__(256) void k_qkv_gemm(const f16* __restrict__ A, const f16* __restrict__ Bt,
                                                  const float* __restrict__ bias,
                                                  f16* __restrict__ Qh, f16* __restrict__ Kf,
                                                  f16* __restrict__ Vf) {
    __shared__ __align__(16) f16 As[128 * 32];
    __shared__ __align__(16) f16 Bs[128 * 32];
    int m0 = blockIdx.x * 128, n0 = blockIdx.y * 128;
    int t = threadIdx.x, lane = t & 63, w = t >> 6;
    int wr = w >> 1, wc = w & 1;
    f32x4 zero = {0.f, 0.f, 0.f, 0.f};
    f32x4 acc[4][4];
#pragma unroll
    for (int i = 0; i < 4; ++i)
#pragma unroll
        for (int j = 0; j < 4; ++j) acc[i][j] = zero;

    gemm_core(A, Bt, m0, n0, lane, w, wr, wc, As, Bs, acc);

    const float QSCALE = 0.18033688011112042f;  // 0.125 * log2(e)
#pragma unroll
    for (int j = 0; j < 4; ++j) {
        int n = n0 + wc * 64 + j * 16 + (lane & 15);
        int which = n / 768;
        int rem = n - which * 768;
        int h = rem >> 6, d = rem & 63;
        float bv = bias[n];
#pragma unroll
        for (int i = 0; i < 4; ++i) {
            int m = m0 + wr * 64 + i * 16 + ((lane >> 4) << 2);
            int bb = m >> 11, tt = m & 2047;
            int bh = bb * 12 + h;
            if (which == 2) {
                int kt = tt >> 6;
                int half = (tt & 63) >> 5, hi = (tt & 31) >> 3, e0 = tt & 7;
                int jd = d >> 4, lo = d & 15;
                size_t addr = (((size_t)bh * 32 + kt) * 8 + jd * 2 + half) * 512 +
                              (size_t)(hi * 16 + lo) * 8 + e0;
                f16x4 pk;
#pragma unroll
                for (int r = 0; r < 4; ++r) pk[r] = (f16)(acc[i][j][r] + bv);
                *(f16x4*)(Vf + addr) = pk;
            } else if (which == 0) {
#pragma unroll
                for (int r = 0; r < 4; ++r)
                    Qh[((size_t)bh * 2048 + tt + r) * 64 + d] = (f16)((acc[i][j][r] + bv) * QSCALE);
            } else {
                int half = d >> 5, hi = (d & 31) >> 3, e = d & 7;
#pragma unroll
                for (int r = 0; r < 4; ++r) {
                    int tr = tt + r;
                    int kt = tr >> 6, row = tr & 63;
                    int s = row >> 4, lo = row & 15;
                    size_t addr = (((size_t)bh * 32 + kt) * 8 + s * 2 + half) * 512 +
                                  (size_t)(hi * 16 + lo) * 8 + e;
                    Kf[addr] = (f16)(acc[i][j][r] + bv);
                }
            }
        }
    }
}

// ---------------- O GEMM ----------------
__global__ __launch_bounds__(256) void k_o_gemm(const f16* __restrict__ A, const f16* __restrict__ Bt,
                                                const float* __restrict__ bias,
                                                float* __restrict__ out) {
    __shared__ __align__(16) f16 As[128 * 32];
    __shared__ __align__(16) f16 Bs[128 * 32];
    int m0 = blockIdx.x * 128, n0 = blockIdx.y * 128;
    int t = threadIdx.x, lane = t & 63, w = t >> 6;
    int wr = w >> 1, wc = w & 1;
    f32x4 zero = {0.f, 0.f, 0.f, 0.f};
    f32x4 acc[4][4];
#pragma unroll
    for (int i = 0; i < 4; ++i)
#pragma unroll
        for (int j = 0; j < 4; ++j) acc[i][j] = zero;

    gemm_core(A, Bt, m0, n0, lane, w, wr, wc, As, Bs, acc);

#pragma unroll
    for (int j = 0; j < 4; ++j) {
        int n = n0 + wc * 64 + j * 16 + (lane & 15);
        float bv = bias[n];
#pragma unroll
        for (int i = 0; i < 4; ++i) {
            int m = m0 + wr * 64 + i * 16 + ((lane >> 4) << 2);
#pragma unroll
            for (int r = 0; r < 4; ++r) out[(size_t)(m + r) * 768 + n] = acc[i][j][r] + bv;
        }
    }
}

// ---------------- lsum: split-k partial row-sums, swapped QK^T (R11 proven) ----------------
__global__ __launch_bounds__(256) void k_lsum(const f16* __restrict__ Qh, const f16* __restrict__ Kf,
                                              float* __restrict__ lpart) {
    int qt = blockIdx.x, bh = blockIdx.y, kc = blockIdx.z;
    int q0 = qt * 64;
    int t = threadIdx.x, lane = t & 63, w = t >> 6;
    const f16* qbase = Qh + ((size_t)bh * 2048 + q0 + w * 16) * 64;
    const f16* kfb = Kf + (size_t)bh * 32 * 4096 + (size_t)lane * 8;

    f16x8 aq[2];
#pragma unroll
    for (int f = 0; f < 2; ++f)
        aq[f] = *(const f16x8*)(qbase + (size_t)(lane & 15) * 64 + f * 32 + (lane >> 4) * 8);
    f32x4 zero = {0.f, 0.f, 0.f, 0.f};

    auto LOADK = [&](f16x8* dst, int kt) {
        const f16* kp = kfb + (size_t)kt * 4096;
#pragma unroll
        for (int f = 0; f < 8; ++f) dst[f] = *(const f16x8*)(kp + f * 512);
    };
    auto QKTS = [&](const f16x8* kf, f32x4* s4) {   // swapped: A=K, B=Q
#pragma unroll
        for (int s = 0; s < 4; ++s) {
            s4[s] = MFMA16(kf[2 * s], aq[0], zero);
            s4[s] = MFMA16(kf[2 * s + 1], aq[1], s4[s]);
        }
    };

    f16x8 ka[8], kb2[8];
    float lsum = 0.f;
    int base = kc * 8;
    LOADK(ka, base);
    for (int i = 0; i < 8; i += 2) {
        f32x4 s4[4];
        LOADK(kb2, base + i + 1);
        QKTS(ka, s4);
#pragma unroll
        for (int s = 0; s < 4; ++s)
#pragma unroll
            for (int r = 0; r < 4; ++r) lsum += fexp2(s4[s][r]);
        LOADK(ka, base + ((i + 2) & 7));
        QKTS(kb2, s4);
#pragma unroll
        for (int s = 0; s < 4; ++s)
#pragma unroll
            for (int r = 0; r < 4; ++r) lsum += fexp2(s4[s][r]);
    }
    lsum += __shfl_xor(lsum, 16, 64);
    lsum += __shfl_xor(lsum, 32, 64);
    float* lp = lpart + (size_t)kc * 49152 + (size_t)bh * 2048 + q0 + w * 16;
    if (lane < 16) lp[lane] = lsum;
}

// ---------------- attention pass 2: 8 waves/block, wave-pairs split the kt range ----------------
// grid 768 x 512 threads. Waves (2qg, 2qg+1) both own q-group qg (16 rows); half 0 streams
// kt 0..15, half 1 streams kt 16..31 (independent: linv precomputed, stores disjoint).
// 2 blocks/CU resident (VGPR<=128) -> 16 waves/CU vs 12 before. K single-buffered
// (reloaded after QK^T consumes it); V loaded first each iteration so load-waits never
// force the 400 MB store stream to retire. PV halves combined through LDS at the end.
__global__ __launch_bounds__(512, 4) void k_attn(const f16* __restrict__ Qh, const f16* __restrict__ Kf,
                                                 const f16* __restrict__ Vf,
                                                 const float* __restrict__ lpart,
                                                 float* __restrict__ attn, f16* __restrict__ valh) {
    __shared__ __align__(16) float Ps32_all[8][16 * 68];
    int orig = blockIdx.x;
    int swz = (orig & 7) * 96 + (orig >> 3);   // 768 blocks, 8 XCDs, bijective
    int bh = swz >> 5, qt = swz & 31;
    int q0 = qt * 64;
    int t = threadIdx.x, lane = t & 63, w = t >> 6;
    int qg = w >> 1, half = w & 1;

    const f16* qbase = Qh + ((size_t)bh * 2048 + q0 + qg * 16) * 64;
    const f16* kfb = Kf + (size_t)bh * 32 * 4096 + (size_t)lane * 8;
    const f16* vfb = Vf + (size_t)bh * 32 * 4096 + (size_t)lane * 8;

    f16x8 aq[2];
#pragma unroll
    for (int f = 0; f < 2; ++f)
        aq[f] = *(const f16x8*)(qbase + (size_t)(lane & 15) * 64 + f * 32 + (lane >> 4) * 8);
    f32x4 zero = {0.f, 0.f, 0.f, 0.f};

    // scalar linv: this lane's q-row = q0 + qg*16 + (lane&15)
    float linv;
    {
        size_t qoff = (size_t)bh * 2048 + q0 + qg * 16 + (lane & 15);
        float s = 0.f;
#pragma unroll
        for (int kc = 0; kc < 4; ++kc) s += lpart[(size_t)kc * 49152 + qoff];
        linv = 1.0f / s;
    }

    auto LOADK = [&](f16x8* dst, int kt) {
        const f16* kp = kfb + (size_t)kt * 4096;
#pragma unroll
        for (int f = 0; f < 8; ++f) dst[f] = *(const f16x8*)(kp + f * 512);
    };

    f32x4 accv[4];
#pragma unroll
    for (int j = 0; j < 4; ++j) accv[j] = zero;
    float* Ps = Ps32_all[w];   // wave-private 16 x 68 f32, [q][k]
    float* attn_base = attn + ((size_t)bh * 2048 + q0 + qg * 16) * 2048;
    f16x8 ka[8], vbuf[8];

    int ktbase = half * 16;
    LOADK(ka, ktbase);
    for (int kt = ktbase; kt < ktbase + 16; ++kt) {
        // 1) V loads first (oldest in-flight)
        {
            const f16* vp = vfb + (size_t)kt * 4096;
#pragma unroll
            for (int f = 0; f < 8; ++f) vbuf[f] = *(const f16x8*)(vp + f * 512);
        }
        // 2) swapped QK^T on current K: lane holds S[k=s*16+(lane>>4)*4+r][q=lane&15]
        f32x4 s4[4];
#pragma unroll
        for (int s = 0; s < 4; ++s) {
            s4[s] = MFMA16(ka[2 * s], aq[0], zero);
            s4[s] = MFMA16(ka[2 * s + 1], aq[1], s4[s]);
        }
        // 3) reload K for next iteration (WAR on ka: issues after MFMAs consume it)
        LOADK(ka, (kt + 1) & 31);
        // 4) softmax -> Ps[q][k]: 4x ds_write_b128
#pragma unroll
        for (int s = 0; s < 4; ++s) {
            f32x4 pv;
#pragma unroll
            for (int r = 0; r < 4; ++r) pv[r] = fexp2(s4[s][r]) * linv;
            *(f32x4*)(Ps + (lane & 15) * 68 + s * 16 + (lane >> 4) * 4) = pv;
        }
        // 5) PV A-fragment (f16) from the tile
        f16x8 pa[2];
#pragma unroll
        for (int hh = 0; hh < 2; ++hh) {
            const float* pr = Ps + (lane & 15) * 68 + hh * 32 + (lane >> 4) * 8;
            f32x4 lo = *(const f32x4*)(pr);
            f32x4 hi = *(const f32x4*)(pr + 4);
            f16x8 pf = {(f16)lo[0], (f16)lo[1], (f16)lo[2], (f16)lo[3],
                        (f16)hi[0], (f16)hi[1], (f16)hi[2], (f16)hi[3]};
            pa[hh] = pf;
        }
        // 6) coalesced attention stores: 4x dwordx4 (256B runs per 16-lane group)
        float* ab = attn_base + kt * 64;
#pragma unroll
        for (int i = 0; i < 4; ++i) {
            int row = i * 4 + (lane >> 4);
            int col = (lane & 15) * 4;
            f32x4 v = *(const f32x4*)(Ps + row * 68 + col);
            *(f32x4*)(ab + (size_t)row * 2048 + col) = v;
        }
        // 7) PV MFMA (waits vbuf; K reload + stores are younger, stay outstanding)
#pragma unroll
        for (int jd = 0; jd < 4; ++jd) {
            accv[jd] = MFMA16(pa[0], vbuf[2 * jd], accv[jd]);
            accv[jd] = MFMA16(pa[1], vbuf[2 * jd + 1], accv[jd]);
        }
    }

    // combine PV halves through LDS, then wave 0 of each pair writes valh
    if (half) {
#pragma unroll
        for (int j = 0; j < 4; ++j)
#pragma unroll
            for (int r = 0; r < 4; ++r)
                Ps[((lane >> 4) * 4 + r) * 68 + j * 16 + (lane & 15)] = accv[j][r];
    }
    __syncthreads();
    if (!half) {
        const float* Pp = Ps32_all[w + 1];
        int b = bh / 12, h = bh - b * 12;
#pragma unroll
        for (int j = 0; j < 4; ++j) {
#pragma unroll
            for (int r = 0; r < 4; ++r) {
                float v = accv[j][r] + Pp[((lane >> 4) * 4 + r) * 68 + j * 16 + (lane & 15)];
                int rowg = b * 2048 + q0 + qg * 16 + (lane >> 4) * 4 + r;
                int col = h * 64 + j * 16 + (lane & 15);
                valh[(size_t)rowg * 768 + col] = (f16)v;
            }
        }
    }
}

extern "C" void kernel_launch(void* const* d_in, const int* in_sizes, int n_in,
                              void* d_out, int out_size, void* d_ws, size_t ws_size,
                              hipStream_t stream) {
    const float* x = (const float*)d_in[0];
    const float* wqkv = (const float*)d_in[1];
    const float* bqkv = (const float*)d_in[2];
    const float* wo = (const float*)d_in[3];
    const float* bo = (const float*)d_in[4];

    float* out_o = (float*)d_out;                          // [2,2048,768] fp32
    float* out_attn = out_o + (size_t)2 * 2048 * 768;      // [2,12,2048,2048] fp32

    f16* ws = (f16*)d_ws;
    f16* xh = ws;                       // 3,145,728 f16
    f16* wqkv_t = xh + 3145728;         // [2304][768]
    f16* wo_t = wqkv_t + 1769472;       // [768][768]
    f16* Qh = wo_t + 589824;            // [bh][t][64], pre-scaled
    f16* Kf = Qh + 3145728;             // fragment-linear K
    f16* Vf = Kf + 3145728;             // fragment-linear V
    f16* valh = Vf + 3145728;           // [4096][768]
    float* lpart = (float*)(valh + 3145728);  // [4][24*2048] f32 split-k partials

    k_convert_x<<<3072, 256, 0, stream>>>(x, xh, 786432);
    k_transpose<<<dim3(36, 12), 256, 0, stream>>>(wqkv, wqkv_t, 768, 2304);
    k_transpose<<<dim3(12, 12), 256, 0, stream>>>(wo, wo_t, 768, 768);
    k_qkv_gemm<<<dim3(32, 18), 256, 0, stream>>>(xh, wqkv_t, bqkv, Qh, Kf, Vf);
    k_lsum<<<dim3(32, 24, 4), 256, 0, stream>>>(Qh, Kf, lpart);
    k_attn<<<768, 512, 0, stream>>>(Qh, Kf, Vf, lpart, out_attn, valh);
    k_o_gemm<<<dim3(32, 6), 256, 0, stream>>>(valh, wo_t, bo, out_o);
}